// Round 4
// baseline (11782.886 us; speedup 1.0000x reference)
//
#include <hip/hip_runtime.h>
#include <hip/hip_cooperative_groups.h>

namespace cg = cooperative_groups;

typedef _Float16 f16;
typedef f16 f16x8 __attribute__((ext_vector_type(8)));
typedef float f32x4 __attribute__((ext_vector_type(4)));

#define TSTEPS 128
#define NBLK 256
#define NTHR 768
#define LDS_BYTES 147456           // 3 sub-groups x 48 KB A-chunk

// ---------------- workspace layout (bytes) ----------------
#define WT_BYTES (3ull*128*32*64*16)            // swizzled f16 weights: 12,582,912
#define H_OFF    (WT_BYTES)
#define H_BYTES  (3ull*2*768*512*2)             // h double buffers (f16): 4,718,592
#define S1_OFF   (H_OFF + H_BYTES)
#define O1_OFF   (S1_OFF + 1536*4)
#define Y1_OFF   (O1_OFF + 1536*4)
#define S2_OFF   (Y1_OFF + 256ull*1024*4)
#define O2_OFF   (S2_OFF + 1024*4)
#define Y2_OFF   (O2_OFF + 1024*4)
#define S3_OFF   (Y2_OFF + 256ull*102*4)
#define O3_OFF   (S3_OFF + 128*4)
#define WS_NEED  (O3_OFF + 128*4)               // ~18.5 MB

struct Params {
  const int *t1, *t2, *t3;
  const float *emb, *lW, *lB;
  const float *g1, *be1, *W1, *b1;
  const float *g2, *be2, *W2, *b2;
  const float *g3, *be3, *W3, *b3;
  float* out;
  unsigned char* ws;
};

__device__ __forceinline__ float sigmf(float x) {
  x = fminf(fmaxf(x, -30.f), 30.f);
  return 1.f / (1.f + __expf(-x));
}
__device__ __forceinline__ float tanhf_(float x) {
  x = fminf(fmaxf(x, -15.f), 15.f);
  float e = __expf(-2.f * x);
  return (1.f - e) / (1.f + e);
}
__device__ __forceinline__ float wsum(float v) {
  #pragma unroll
  for (int m = 1; m < 64; m <<= 1) v += __shfl_xor(v, m, 64);
  return v;
}
// async global->LDS DMA, 16 B/lane; LDS dest = wave-uniform base + lane*16
__device__ __forceinline__ void gld_lds16(const f16* g, f16* l) {
  __builtin_amdgcn_global_load_lds(
      (const __attribute__((address_space(1))) unsigned int*)g,
      (__attribute__((address_space(3))) unsigned int*)l, 16, 0, 0);
}
#define MFMA16(a,b,c) __builtin_amdgcn_mfma_f32_16x16x32_f16((a),(b),(c),0,0,0)

// 256 blocks x 768 threads (proven cooperative shape), 1 block/CU, 12 waves.
__global__ __launch_bounds__(NTHR, 3) void conv_lstm(Params P) {
  cg::grid_group grid = cg::this_grid();
  const int bid = blockIdx.x, tid = threadIdx.x;

  extern __shared__ __align__(16) f16 smem[];   // 3 x 24576 f16 (48 KB each)

  f16* WT = (f16*)(P.ws);
  f16* Hb = (f16*)(P.ws + H_OFF);

  // ---- phase -1: weight f32->f16 swizzle into MFMA B-fragment order + zero h ----
  {
    const int gt = bid * NTHR + tid;
    for (int slot = gt; slot < 786432; slot += NBLK * NTHR) {
      int lane = slot & 63, kkg = (slot >> 6) & 31, g16 = (slot >> 11) & 127, l = slot >> 18;
      int k = kkg * 32 + (lane >> 4) * 8;
      int p = g16 * 16 + (lane & 15);             // permuted gate-col: p = 4u+g
      int n = (p & 3) * 512 + (p >> 2);           // original col: g*512+u
      const float* s = P.lW + ((size_t)l * 1024 + k) * 2048 + n;
      f16x8 v;
      #pragma unroll
      for (int j = 0; j < 8; j++) v[j] = (f16)s[(size_t)j * 2048];
      *(f16x8*)(WT + (size_t)slot * 8) = v;
    }
    uint4 z4; z4.x = z4.y = z4.z = z4.w = 0u;
    uint4* zp = (uint4*)(P.ws + H_OFF);
    for (int i = gt; i < 294912; i += NBLK * NTHR) zp[i] = z4;
  }
  grid.sync();

  // ---- thread geometry ----
  const int sb   = tid >> 8;                      // layer sub-group (256 thr = 4 waves)
  const int tid2 = tid & 255;
  const int w2   = tid2 >> 6, L = tid2 & 63;
  const int wrg  = w2 >> 1, wct = w2 & 1;
  const int r16  = L & 15, quad = L >> 4;
  const int s4   = L & 3, r16q = r16 >> 2;
  const int rg   = bid >> 5, cgi = bid & 31;      // bid%8 = cgi%8 -> weight slice L2-local/XCD
  const int row0 = rg * 96;

  f16* sg    = smem + sb * 24576;                 // this layer's A region (48 KB)
  const int ug = cgi * 16 + wct * 8 + r16q;
  float bia[2][4];
  #pragma unroll
  for (int ct2 = 0; ct2 < 2; ++ct2)
    #pragma unroll
    for (int g = 0; g < 4; ++g)
      bia[ct2][g] = P.lB[sb * 2048 + g * 512 + ug + ct2 * 4];
  float c6[6] = {0.f, 0.f, 0.f, 0.f, 0.f, 0.f};   // persistent c-state (VGPR)

  const size_t lstride = 768 * 512;
  const f16x8* Bb = (const f16x8*)WT
      + ((size_t)(sb * 128 + cgi * 4 + wct * 2) * 32) * 64 + L;

  // ---- wavefront: 3 layers in parallel; A staged to LDS via global_load_lds ----
  for (int s = 0; s < TSTEPS + 2; ++s) {
    const int t = s - sb;
    const bool act = (t >= 0 && t < TSTEPS);
    const f16* hx  = Hb + (size_t)((sb ? sb - 1 : 0) * 2 + (t & 1)) * lstride;
    const f16* hh  = Hb + (size_t)(sb * 2 + ((t - 1) & 1)) * lstride;
    f16*       hdo = Hb + (size_t)(sb * 2 + (t & 1)) * lstride;

    f32x4 acc[3][2];
    #pragma unroll
    for (int a = 0; a < 3; a++)
      #pragma unroll
      for (int b = 0; b < 2; b++) acc[a][b] = (f32x4){0.f, 0.f, 0.f, 0.f};

    for (int chunk = 0; chunk < 4; ++chunk) {     // K=1024 in 4 x 256
      __syncthreads();                            // LDS buffer free (uniform)
      if (act) {
        // wave w2 stages frag-blocks fb = w2*12 .. +11; fb = rt6*8+kk (1 KB each)
        #pragma unroll
        for (int i = 0; i < 12; ++i) {
          int fb = w2 * 12 + i;
          int rt6 = fb >> 3, kk = fb & 7;
          int m = row0 + rt6 * 16 + r16;          // per-lane row
          int k = chunk * 256 + kk * 32 + quad * 8;
          f16* dst = sg + fb * 512 + L * 8;       // frag-block, lane-contiguous
          if (chunk < 2) {                        // x-part (k < 512)
            if (sb == 0) {                        // emb f32 -> f16 via VGPR
              int b = m & 255, tx = m >> 8;
              const int* tp = (tx == 0) ? P.t1 : ((tx == 1) ? P.t2 : P.t3);
              int tok = tp[b * TSTEPS + t];
              const float* e = P.emb + (size_t)tok * 512 + k;
              float4 fa = *(const float4*)e, fb2 = *(const float4*)(e + 4);
              f16x8 v;
              v[0]=(f16)fa.x;  v[1]=(f16)fa.y;  v[2]=(f16)fa.z;  v[3]=(f16)fa.w;
              v[4]=(f16)fb2.x; v[5]=(f16)fb2.y; v[6]=(f16)fb2.z; v[7]=(f16)fb2.w;
              *(f16x8*)dst = v;
            } else {
              gld_lds16(hx + (size_t)m * 512 + k, dst);
            }
          } else {                                // h-part
            gld_lds16(hh + (size_t)m * 512 + (k - 512), dst);
          }
        }
      }
      __syncthreads();                            // staging complete (vmcnt drained)
      if (act) {
        const f16x8* Bc = Bb + (size_t)(chunk * 8) * 64;
        #pragma unroll 4
        for (int kk = 0; kk < 8; ++kk) {
          f16x8 a0 = *(const f16x8*)(sg + ((wrg * 3 + 0) * 8 + kk) * 512 + L * 8);
          f16x8 a1 = *(const f16x8*)(sg + ((wrg * 3 + 1) * 8 + kk) * 512 + L * 8);
          f16x8 a2 = *(const f16x8*)(sg + ((wrg * 3 + 2) * 8 + kk) * 512 + L * 8);
          f16x8 b0 = Bc[kk * 64];
          f16x8 b1 = Bc[kk * 64 + 2048];
          acc[0][0] = MFMA16(a0, b0, acc[0][0]);
          acc[1][0] = MFMA16(a1, b0, acc[1][0]);
          acc[2][0] = MFMA16(a2, b0, acc[2][0]);
          acc[0][1] = MFMA16(a0, b1, acc[0][1]);
          acc[1][1] = MFMA16(a1, b1, acc[1][1]);
          acc[2][1] = MFMA16(a2, b1, acc[2][1]);
        }
      }
    }

    // ---- elementwise: 4x4 lane<->reg transpose -> c/h; h via LDS stash ----
    __syncthreads();                              // A region free for stash (uniform)
    f16* stash = sg;                              // [96][18] f16 (stride 18 breaks banks)
    if (act) {
      #pragma unroll
      for (int rt = 0; rt < 3; ++rt) {
        #pragma unroll
        for (int ct2 = 0; ct2 < 2; ++ct2) {
          float x0 = acc[rt][ct2][0], x1 = acc[rt][ct2][1];
          float x2 = acc[rt][ct2][2], x3 = acc[rt][ct2][3];
          float a, b;
          a = (s4 & 1) ? x0 : x1;  b = (s4 & 1) ? x2 : x3;
          a = __shfl_xor(a, 1, 64); b = __shfl_xor(b, 1, 64);
          if (s4 & 1) { x0 = a; x2 = b; } else { x1 = a; x3 = b; }
          a = (s4 & 2) ? x0 : x2;  b = (s4 & 2) ? x1 : x3;
          a = __shfl_xor(a, 2, 64); b = __shfl_xor(b, 2, 64);
          if (s4 & 2) { x0 = a; x1 = b; } else { x2 = a; x3 = b; }
          // lane holds {i,j,f,o} for row_local, col_local
          float vi = x0 + bia[ct2][0], vj = x1 + bia[ct2][1];
          float vf = x2 + bia[ct2][2], vo = x3 + bia[ct2][3];
          int j = rt * 2 + ct2;
          float cn = sigmf(vf) * c6[j] + sigmf(vi) * tanhf_(vj);
          c6[j] = cn;
          int rl = wrg * 48 + rt * 16 + quad * 4 + s4;
          int cl = wct * 8 + ct2 * 4 + r16q;
          stash[rl * 18 + cl] = (f16)(sigmf(vo) * tanhf_(cn));
        }
      }
    }
    __syncthreads();                              // stash complete (uniform)
    if (act && tid2 < 192) {                      // coalesced 16 B h-stores
      int rl = tid2 >> 1, half = tid2 & 1;
      uint4 v = *(const uint4*)(stash + rl * 18 + half * 8);
      *(uint4*)(hdo + (size_t)(row0 + rl) * 512 + cgi * 16 + half * 8) = v;
    }
    grid.sync();
  }

  // ---------------- epilogue (wave-granular, shfl-only; verbatim from R3) ----------------
  float* scale1 = (float*)(P.ws + S1_OFF); float* off1 = (float*)(P.ws + O1_OFF);
  float* y1     = (float*)(P.ws + Y1_OFF);
  float* scale2 = (float*)(P.ws + S2_OFF); float* off2 = (float*)(P.ws + O2_OFF);
  float* y2     = (float*)(P.ws + Y2_OFF);
  float* scale3 = (float*)(P.ws + S3_OFF); float* off3 = (float*)(P.ws + O3_OFF);
  const f16* h2f = Hb + (size_t)(2 * 2 + 1) * lstride;   // top layer, t=127 (slot 1)

  const int wvg = bid * 12 + (tid >> 6);
  const int Le  = tid & 63;
  const float SC = 1.0507009873554805f, AL = 1.6732632423543772f;

  // E1: BN1 -> fused scale/offset for 1536 cols
  if (wvg < 1536) {
    int c = wvg, tx = c >> 9, u = c & 511;
    float sm = 0.f, s2 = 0.f;
    for (int r = Le; r < 256; r += 64) {
      float v = (float)h2f[(size_t)(tx * 256 + r) * 512 + u];
      sm += v; s2 += v * v;
    }
    sm = wsum(sm); s2 = wsum(s2);
    if (Le == 0) {
      float mu = sm * (1.f / 256.f);
      float var = s2 * (1.f / 256.f) - mu * mu;
      float sc = rsqrtf(var + 1e-3f) * P.g1[c];
      scale1[c] = sc; off1[c] = P.be1[c] - mu * sc;
    }
  }
  grid.sync();

  // E2: y1 = selu(rep_n @ W1 + b1): 1024 waves, tile 16 rows x 16 cols
  if (wvg < 1024) {
    int rb = wvg >> 6, cb = wvg & 63;
    int cL = Le & 15, rq = Le >> 4;
    int col = cb * 16 + cL;
    float accv[4] = {0.f, 0.f, 0.f, 0.f};
    for (int k = 0; k < 1536; ++k) {
      int tx = k >> 9, u = k & 511;
      float sc = scale1[k], of = off1[k];
      float wv = P.W1[(size_t)k * 1024 + col];
      #pragma unroll
      for (int rr = 0; rr < 4; ++rr) {
        int row = rb * 16 + rq * 4 + rr;
        float v = (float)h2f[(size_t)(tx * 256 + row) * 512 + u] * sc + of;
        accv[rr] += v * wv;
      }
    }
    #pragma unroll
    for (int rr = 0; rr < 4; ++rr) {
      int row = rb * 16 + rq * 4 + rr;
      float x = accv[rr] + P.b1[col];
      y1[(size_t)row * 1024 + col] = SC * (x > 0.f ? x : AL * expm1f(x));
    }
  }
  grid.sync();

  // E3: BN2 scale/offset for 1024 cols
  if (wvg < 1024) {
    int c = wvg;
    float sm = 0.f, s2 = 0.f;
    for (int r = Le; r < 256; r += 64) {
      float v = y1[(size_t)r * 1024 + c];
      sm += v; s2 += v * v;
    }
    sm = wsum(sm); s2 = wsum(s2);
    if (Le == 0) {
      float mu = sm * (1.f / 256.f);
      float var = s2 * (1.f / 256.f) - mu * mu;
      float sc = rsqrtf(var + 1e-3f) * P.g2[c];
      scale2[c] = sc; off2[c] = P.be2[c] - mu * sc;
    }
  }
  grid.sync();

  // E4: y2 = selu(y1n @ W2 + b2): one wave per batch row
  if (wvg < 256) {
    int row = wvg;
    int c0 = Le, c1 = Le + 64;
    float a0 = 0.f, a1 = 0.f;
    for (int k = 0; k < 1024; ++k) {
      float v = y1[(size_t)row * 1024 + k] * scale2[k] + off2[k];
      a0 += v * P.W2[(size_t)k * 102 + c0];
      if (c1 < 102) a1 += v * P.W2[(size_t)k * 102 + c1];
    }
    {
      float x = a0 + P.b2[c0];
      if (c0 < 102) y2[(size_t)row * 102 + c0] = SC * (x > 0.f ? x : AL * expm1f(x));
    }
    if (c1 < 102) {
      float x = a1 + P.b2[c1];
      y2[(size_t)row * 102 + c1] = SC * (x > 0.f ? x : AL * expm1f(x));
    }
  }
  grid.sync();

  // E5: BN3 scale/offset for 102 cols
  if (wvg < 102) {
    int c = wvg;
    float sm = 0.f, s2 = 0.f;
    for (int r = Le; r < 256; r += 64) {
      float v = y2[(size_t)r * 102 + c];
      sm += v; s2 += v * v;
    }
    sm = wsum(sm); s2 = wsum(s2);
    if (Le == 0) {
      float mu = sm * (1.f / 256.f);
      float var = s2 * (1.f / 256.f) - mu * mu;
      float sc = rsqrtf(var + 1e-3f) * P.g3[c];
      scale3[c] = sc; off3[c] = P.be3[c] - mu * sc;
    }
  }
  grid.sync();

  // E6: out = y2n @ W3 + b3: one wave per batch row
  if (wvg < 256) {
    int row = wvg;
    int c = Le & 3, kq = Le >> 2;
    float part = 0.f;
    for (int k = kq; k < 102; k += 16) {
      float v = y2[(size_t)row * 102 + k] * scale3[k] + off3[k];
      part += v * P.W3[k * 4 + c];
    }
    #pragma unroll
    for (int m = 4; m < 64; m <<= 1) part += __shfl_xor(part, m, 64);
    if (Le < 4) P.out[row * 4 + Le] = part + P.b3[Le];
  }
}

extern "C" void kernel_launch(void* const* d_in, const int* in_sizes, int n_in,
                              void* d_out, int out_size, void* d_ws, size_t ws_size,
                              hipStream_t stream) {
  if (ws_size < (size_t)WS_NEED) return;
  // idempotent, host-side, not a stream op: allow 144 KB dynamic LDS
  (void)hipFuncSetAttribute((const void*)conv_lstm,
                            hipFuncAttributeMaxDynamicSharedMemorySize, LDS_BYTES);
  Params prm;
  prm.t1  = (const int*)d_in[0];
  prm.t2  = (const int*)d_in[1];
  prm.t3  = (const int*)d_in[2];
  prm.emb = (const float*)d_in[3];
  prm.lW  = (const float*)d_in[4];
  prm.lB  = (const float*)d_in[5];
  prm.g1  = (const float*)d_in[6];  prm.be1 = (const float*)d_in[7];
  prm.W1  = (const float*)d_in[8];  prm.b1  = (const float*)d_in[9];
  prm.g2  = (const float*)d_in[10]; prm.be2 = (const float*)d_in[11];
  prm.W2  = (const float*)d_in[12]; prm.b2  = (const float*)d_in[13];
  prm.g3  = (const float*)d_in[14]; prm.be3 = (const float*)d_in[15];
  prm.W3  = (const float*)d_in[16]; prm.b3  = (const float*)d_in[17];
  prm.out = (float*)d_out;
  prm.ws  = (unsigned char*)d_ws;
  void* args[] = { &prm };
  hipLaunchCooperativeKernel((void*)conv_lstm, dim3(NBLK), dim3(NTHR), args,
                             LDS_BYTES, stream);
}

// Round 5
// 7684.576 us; speedup vs baseline: 1.5333x; 1.5333x over previous
//
#include <hip/hip_runtime.h>
#include <hip/hip_cooperative_groups.h>

namespace cg = cooperative_groups;

typedef _Float16 f16;
typedef f16 f16x8 __attribute__((ext_vector_type(8)));
typedef float f32x4 __attribute__((ext_vector_type(4)));
typedef unsigned int u32x4 __attribute__((ext_vector_type(4)));

#define TSTEPS 128
#define NBLK 256
#define NTHR 768
#define LDS_BYTES 147456           // 3 sub-groups x 48 KB A-chunk (also reused by E2)

// ---------------- workspace layout (bytes) ----------------
#define WT_BYTES (3ull*128*32*64*16)            // swizzled f16 weights: 12,582,912
#define H_OFF    (WT_BYTES)
#define H_BYTES  (3ull*2*768*512*2)             // h double buffers (f16): 4,718,592
#define S1_OFF   (H_OFF + H_BYTES)
#define O1_OFF   (S1_OFF + 1536*4)
#define Y1_OFF   (O1_OFF + 1536*4)
#define S2_OFF   (Y1_OFF + 256ull*1024*4)
#define O2_OFF   (S2_OFF + 1024*4)
#define Y2_OFF   (O2_OFF + 1024*4)
#define S3_OFF   (Y2_OFF + 256ull*102*4)
#define O3_OFF   (S3_OFF + 128*4)
#define BAR_OFF  (O3_OFF + 128*4)               // flag counters (zeroed in init)
#define WS_NEED  (BAR_OFF + 1024)

struct Params {
  const int *t1, *t2, *t3;
  const float *emb, *lW, *lB;
  const float *g1, *be1, *W1, *b1;
  const float *g2, *be2, *W2, *b2;
  const float *g3, *be3, *W3, *b3;
  float* out;
  unsigned char* ws;
};

__device__ __forceinline__ float sigmf(float x) {
  x = fminf(fmaxf(x, -30.f), 30.f);
  return 1.f / (1.f + __expf(-x));
}
__device__ __forceinline__ float tanhf_(float x) {
  x = fminf(fmaxf(x, -15.f), 15.f);
  float e = __expf(-2.f * x);
  return (1.f - e) / (1.f + e);
}
__device__ __forceinline__ float wsum(float v) {
  #pragma unroll
  for (int m = 1; m < 64; m <<= 1) v += __shfl_xor(v, m, 64);
  return v;
}
// cache-bypassing (coherence-point) scalar accessors: volatile => sc0/sc1
__device__ __forceinline__ float vldh(const f16* p) {
  unsigned short u = *(volatile const unsigned short*)p;
  union { unsigned short s; f16 h; } cv; cv.s = u;
  return (float)cv.h;
}
__device__ __forceinline__ float vldf(const float* p) { return *(volatile const float*)p; }
__device__ __forceinline__ void  vstf(float* p, float v) { *(volatile float*)p = v; }

// Relaxed flag barrier: NO acquire/release cache ops => L2 stays warm.
// Visibility of prior volatile stores is guaranteed by the s_waitcnt vmcnt(0)
// the compiler emits before s_barrier (each wave drains its own stores before
// the arriving thread can increment the counter).
__device__ __forceinline__ void bar_arrive_wait(unsigned* ctr, unsigned target, int tid) {
  __syncthreads();
  if (tid == 0)
    __hip_atomic_fetch_add(ctr, 1u, __ATOMIC_RELAXED, __HIP_MEMORY_SCOPE_AGENT);
  if (tid < 64) {
    while (__hip_atomic_load(ctr, __ATOMIC_RELAXED, __HIP_MEMORY_SCOPE_AGENT) < target)
      __builtin_amdgcn_s_sleep(8);
  }
  __syncthreads();
}

#define MFMA16(a,b,c) __builtin_amdgcn_mfma_f32_16x16x32_f16((a),(b),(c),0,0,0)

// 256 blocks x 768 threads (proven cooperative shape), 1 block/CU, 12 waves.
__global__ __launch_bounds__(NTHR, 3) void conv_lstm(Params P) {
  cg::grid_group grid = cg::this_grid();
  const int bid = blockIdx.x, tid = threadIdx.x;

  extern __shared__ __align__(16) f16 smem[];   // 3 x 24576 f16 (48 KB each)

  f16*      WT   = (f16*)(P.ws);
  f16*      Hb   = (f16*)(P.ws + H_OFF);
  unsigned* bar  = (unsigned*)(P.ws + BAR_OFF); // [rg*16] rg-ctrs, [128] grid ctr
  unsigned* gctr = bar + 128;

  // ---- phase -1: weight swizzle (normal stores), zero h, zero barrier ctrs ----
  {
    const int gt = bid * NTHR + tid;
    for (int slot = gt; slot < 786432; slot += NBLK * NTHR) {
      int lane = slot & 63, kkg = (slot >> 6) & 31, g16 = (slot >> 11) & 127, l = slot >> 18;
      int k = kkg * 32 + (lane >> 4) * 8;
      int p = g16 * 16 + (lane & 15);             // permuted gate-col: p = 4u+g
      int n = (p & 3) * 512 + (p >> 2);           // original col: g*512+u
      const float* s = P.lW + ((size_t)l * 1024 + k) * 2048 + n;
      f16x8 v;
      #pragma unroll
      for (int j = 0; j < 8; j++) v[j] = (f16)s[(size_t)j * 2048];
      *(f16x8*)(WT + (size_t)slot * 8) = v;
    }
    uint4 z4; z4.x = z4.y = z4.z = z4.w = 0u;
    uint4* zp = (uint4*)(P.ws + H_OFF);
    for (int i = gt; i < 294912; i += NBLK * NTHR) zp[i] = z4;
    if (bid == 0 && tid < 256) bar[tid] = 0u;
  }
  grid.sync();   // the ONE fence-ful sync: publishes WT/h-zeros/ctr-zeros everywhere

  // ---- thread geometry ----
  const int sb   = tid >> 8;                      // layer sub-group (256 thr = 4 waves)
  const int tid2 = tid & 255;
  const int w2   = tid2 >> 6, L = tid2 & 63;
  const int wrg  = w2 >> 1, wct = w2 & 1;
  const int r16  = L & 15, quad = L >> 4;
  const int s4   = L & 3, r16q = r16 >> 2;
  const int rg   = bid >> 5, cgi = bid & 31;      // bid%8 = cgi%8 -> weight slice L2-local/XCD
  const int row0 = rg * 96;
  unsigned* rgc  = bar + rg * 16;

  f16* sg = smem + sb * 24576;                    // this layer's A region (48 KB)
  const int ug = cgi * 16 + wct * 8 + r16q;
  float bia[2][4];
  #pragma unroll
  for (int ct2 = 0; ct2 < 2; ++ct2)
    #pragma unroll
    for (int g = 0; g < 4; ++g)
      bia[ct2][g] = P.lB[sb * 2048 + g * 512 + ug + ct2 * 4];
  float c6[6] = {0.f, 0.f, 0.f, 0.f, 0.f, 0.f};   // persistent c-state (VGPR)

  const size_t lstride = 768 * 512;
  const f16x8* Bb = (const f16x8*)WT
      + ((size_t)(sb * 128 + cgi * 4 + wct * 2) * 32) * 64 + L;

  // ---- wavefront: 3 layers parallel; h exchanged ONLY via L3 (volatile); ----
  // ---- per-rg relaxed barriers: zero cache invalidation in the loop.      ----
  for (int s = 0; s < TSTEPS + 2; ++s) {
    const int t = s - sb;
    const bool act = (t >= 0 && t < TSTEPS);
    const f16* hx  = Hb + (size_t)((sb ? sb - 1 : 0) * 2 + (t & 1)) * lstride;
    const f16* hh  = Hb + (size_t)(sb * 2 + ((t - 1) & 1)) * lstride;
    f16*       hdo = Hb + (size_t)(sb * 2 + (t & 1)) * lstride;

    f32x4 acc[3][2];
    #pragma unroll
    for (int a = 0; a < 3; a++)
      #pragma unroll
      for (int b = 0; b < 2; b++) acc[a][b] = (f32x4){0.f, 0.f, 0.f, 0.f};

    for (int chunk = 0; chunk < 4; ++chunk) {     // K=1024 in 4 x 256
      __syncthreads();                            // LDS region reusable
      if (act) {
        #pragma unroll
        for (int i = 0; i < 12; ++i) {            // wave stages 12 x 1KB frag-blocks
          int fb = w2 * 12 + i;
          int rt6 = fb >> 3, kk = fb & 7;
          int m = row0 + rt6 * 16 + r16;
          int k = chunk * 256 + kk * 32 + quad * 8;
          f16* dst = sg + fb * 512 + L * 8;
          if (chunk < 2) {                        // x-part (k < 512)
            if (sb == 0) {                        // emb f32 -> f16 (normal, L2/L3 cached)
              int b = m & 255, tx = m >> 8;
              const int* tp = (tx == 0) ? P.t1 : ((tx == 1) ? P.t2 : P.t3);
              int tok = tp[b * TSTEPS + t];
              const float* e = P.emb + (size_t)tok * 512 + k;
              float4 fa = *(const float4*)e, fb2 = *(const float4*)(e + 4);
              f16x8 v;
              v[0]=(f16)fa.x;  v[1]=(f16)fa.y;  v[2]=(f16)fa.z;  v[3]=(f16)fa.w;
              v[4]=(f16)fb2.x; v[5]=(f16)fb2.y; v[6]=(f16)fb2.z; v[7]=(f16)fb2.w;
              *(f16x8*)dst = v;
            } else {                              // h of layer below: L3-coherent read
              u32x4 v = *(volatile const u32x4*)(hx + (size_t)m * 512 + k);
              *(u32x4*)dst = v;
            }
          } else {                                // own h_{t-1}: L3-coherent read
            u32x4 v = *(volatile const u32x4*)(hh + (size_t)m * 512 + (k - 512));
            *(u32x4*)dst = v;
          }
        }
      }
      __syncthreads();                            // staging visible block-wide
      if (act) {
        const f16x8* Bc = Bb + (size_t)(chunk * 8) * 64;   // B: normal loads, L2-resident
        #pragma unroll 4
        for (int kk = 0; kk < 8; ++kk) {
          f16x8 a0 = *(const f16x8*)(sg + ((wrg * 3 + 0) * 8 + kk) * 512 + L * 8);
          f16x8 a1 = *(const f16x8*)(sg + ((wrg * 3 + 1) * 8 + kk) * 512 + L * 8);
          f16x8 a2 = *(const f16x8*)(sg + ((wrg * 3 + 2) * 8 + kk) * 512 + L * 8);
          f16x8 b0 = Bc[kk * 64];
          f16x8 b1 = Bc[kk * 64 + 2048];
          acc[0][0] = MFMA16(a0, b0, acc[0][0]);
          acc[1][0] = MFMA16(a1, b0, acc[1][0]);
          acc[2][0] = MFMA16(a2, b0, acc[2][0]);
          acc[0][1] = MFMA16(a0, b1, acc[0][1]);
          acc[1][1] = MFMA16(a1, b1, acc[1][1]);
          acc[2][1] = MFMA16(a2, b1, acc[2][1]);
        }
      }
    }

    // ---- elementwise: 4x4 lane<->reg transpose -> c/h; h out via LDS stash ----
    __syncthreads();
    f16* stash = sg;                              // [96][18] f16
    if (act) {
      #pragma unroll
      for (int rt = 0; rt < 3; ++rt) {
        #pragma unroll
        for (int ct2 = 0; ct2 < 2; ++ct2) {
          float x0 = acc[rt][ct2][0], x1 = acc[rt][ct2][1];
          float x2 = acc[rt][ct2][2], x3 = acc[rt][ct2][3];
          float a, b;
          a = (s4 & 1) ? x0 : x1;  b = (s4 & 1) ? x2 : x3;
          a = __shfl_xor(a, 1, 64); b = __shfl_xor(b, 1, 64);
          if (s4 & 1) { x0 = a; x2 = b; } else { x1 = a; x3 = b; }
          a = (s4 & 2) ? x0 : x2;  b = (s4 & 2) ? x1 : x3;
          a = __shfl_xor(a, 2, 64); b = __shfl_xor(b, 2, 64);
          if (s4 & 2) { x0 = a; x1 = b; } else { x2 = a; x3 = b; }
          float vi = x0 + bia[ct2][0], vj = x1 + bia[ct2][1];
          float vf = x2 + bia[ct2][2], vo = x3 + bia[ct2][3];
          int j = rt * 2 + ct2;
          float cn = sigmf(vf) * c6[j] + sigmf(vi) * tanhf_(vj);
          c6[j] = cn;
          int rl = wrg * 48 + rt * 16 + quad * 4 + s4;
          int cl = wct * 8 + ct2 * 4 + r16q;
          stash[rl * 18 + cl] = (f16)(sigmf(vo) * tanhf_(cn));
        }
      }
    }
    __syncthreads();
    if (act && tid2 < 192) {                      // h-store: 16 B write-through to L3
      int rl = tid2 >> 1, half = tid2 & 1;
      u32x4 v = *(const u32x4*)(stash + rl * 18 + half * 8);
      *(volatile u32x4*)(hdo + (size_t)(row0 + rl) * 512 + cgi * 16 + half * 8) = v;
    }
    bar_arrive_wait(rgc, 32u * (unsigned)(s + 1), tid);  // per-rg, relaxed
  }

  // ---------------- epilogue: relaxed grid barriers + volatile buffers ----------------
  float* scale1 = (float*)(P.ws + S1_OFF); float* off1 = (float*)(P.ws + O1_OFF);
  float* y1    = (float*)(P.ws + Y1_OFF);
  float* scale2 = (float*)(P.ws + S2_OFF); float* off2 = (float*)(P.ws + O2_OFF);
  float* y2    = (float*)(P.ws + Y2_OFF);
  float* scale3 = (float*)(P.ws + S3_OFF); float* off3 = (float*)(P.ws + O3_OFF);
  const f16* h2f = Hb + (size_t)(2 * 2 + 1) * lstride;   // top layer, t=127 (slot 1)

  bar_arrive_wait(gctr, 256u, tid);               // all rgs done -> h2f complete

  const int wvg = bid * 12 + (tid >> 6);
  const int Le  = tid & 63;
  const float SC = 1.0507009873554805f, AL = 1.6732632423543772f;

  // E1: BN1 -> fused scale/offset for 1536 cols (one wave per col)
  if (wvg < 1536) {
    int c = wvg, tx = c >> 9, u = c & 511;
    float sm = 0.f, s2 = 0.f;
    for (int r = Le; r < 256; r += 64) {
      float v = vldh(h2f + (size_t)(tx * 256 + r) * 512 + u);
      sm += v; s2 += v * v;
    }
    sm = wsum(sm); s2 = wsum(s2);
    if (Le == 0) {
      float mu = sm * (1.f / 256.f);
      float var = s2 * (1.f / 256.f) - mu * mu;
      float sc = rsqrtf(var + 1e-3f) * P.g1[c];
      vstf(scale1 + c, sc); vstf(off1 + c, P.be1[c] - mu * sc);
    }
  }
  bar_arrive_wait(gctr, 512u, tid);

  // E2: y1 = selu(rep_n @ W1 + b1): block = 16-row slab x 64-col slice, slab in LDS
  {
    const int rb16 = (bid >> 4) * 16, cb = bid & 15;
    f16*   slab = smem;                           // [16][1536] f16 (49,152 B)
    float* scl  = (float*)(smem + 24576);         // [1536]
    float* ofl  = scl + 1536;                     // [1536]
    for (int e = tid; e < 3072; e += NTHR) {      // 16-B chunks of the slab
      int r = e / 192, seg = e % 192;
      int u8 = seg * 8, tx = u8 >> 9, u = u8 & 511;
      u32x4 v = *(volatile const u32x4*)(h2f + (size_t)(tx * 256 + rb16 + r) * 512 + u);
      *(u32x4*)(slab + r * 1536 + seg * 8) = v;
    }
    for (int k2 = tid; k2 < 1536; k2 += NTHR) { scl[k2] = vldf(scale1 + k2); ofl[k2] = vldf(off1 + k2); }
    __syncthreads();
    int rgrp = tid >> 6;
    if (rgrp < 8) {
      int c = cb * 64 + (tid & 63);
      int r0 = rgrp * 2, r1 = r0 + 1;
      float a0 = 0.f, a1 = 0.f;
      for (int k = 0; k < 1536; ++k) {
        float w = P.W1[(size_t)k * 1024 + c];
        float sck = scl[k], ofk = ofl[k];
        a0 += ((float)slab[r0 * 1536 + k] * sck + ofk) * w;
        a1 += ((float)slab[r1 * 1536 + k] * sck + ofk) * w;
      }
      float x0 = a0 + P.b1[c], x1 = a1 + P.b1[c];
      vstf(y1 + (size_t)(rb16 + r0) * 1024 + c, SC * (x0 > 0.f ? x0 : AL * expm1f(x0)));
      vstf(y1 + (size_t)(rb16 + r1) * 1024 + c, SC * (x1 > 0.f ? x1 : AL * expm1f(x1)));
    }
  }
  bar_arrive_wait(gctr, 768u, tid);

  // E3: BN2 scale/offset for 1024 cols (one wave per col)
  if (wvg < 1024) {
    int c = wvg;
    float sm = 0.f, s2 = 0.f;
    for (int r = Le; r < 256; r += 64) {
      float v = vldf(y1 + (size_t)r * 1024 + c);
      sm += v; s2 += v * v;
    }
    sm = wsum(sm); s2 = wsum(s2);
    if (Le == 0) {
      float mu = sm * (1.f / 256.f);
      float var = s2 * (1.f / 256.f) - mu * mu;
      float sc = rsqrtf(var + 1e-3f) * P.g2[c];
      vstf(scale2 + c, sc); vstf(off2 + c, P.be2[c] - mu * sc);
    }
  }
  bar_arrive_wait(gctr, 1024u, tid);

  // E4: y2 = selu(y1n @ W2 + b2): one wave per batch row
  if (wvg < 256) {
    int row = wvg;
    int c0 = Le, c1 = Le + 64;
    float a0 = 0.f, a1 = 0.f;
    for (int k = 0; k < 1024; ++k) {
      float v = vldf(y1 + (size_t)row * 1024 + k) * vldf(scale2 + k) + vldf(off2 + k);
      a0 += v * P.W2[(size_t)k * 102 + c0];
      if (c1 < 102) a1 += v * P.W2[(size_t)k * 102 + c1];
    }
    {
      float x = a0 + P.b2[c0];
      if (c0 < 102) vstf(y2 + (size_t)row * 102 + c0, SC * (x > 0.f ? x : AL * expm1f(x)));
    }
    if (c1 < 102) {
      float x = a1 + P.b2[c1];
      vstf(y2 + (size_t)row * 102 + c1, SC * (x > 0.f ? x : AL * expm1f(x)));
    }
  }
  bar_arrive_wait(gctr, 1280u, tid);

  // E5: BN3 scale/offset for 102 cols (one wave per col)
  if (wvg < 102) {
    int c = wvg;
    float sm = 0.f, s2 = 0.f;
    for (int r = Le; r < 256; r += 64) {
      float v = vldf(y2 + (size_t)r * 102 + c);
      sm += v; s2 += v * v;
    }
    sm = wsum(sm); s2 = wsum(s2);
    if (Le == 0) {
      float mu = sm * (1.f / 256.f);
      float var = s2 * (1.f / 256.f) - mu * mu;
      float sc = rsqrtf(var + 1e-3f) * P.g3[c];
      vstf(scale3 + c, sc); vstf(off3 + c, P.be3[c] - mu * sc);
    }
  }
  bar_arrive_wait(gctr, 1536u, tid);

  // E6: out = y2n @ W3 + b3: one wave per batch row
  if (wvg < 256) {
    int row = wvg;
    int c = Le & 3, kq = Le >> 2;
    float part = 0.f;
    for (int k = kq; k < 102; k += 16) {
      float v = vldf(y2 + (size_t)row * 102 + k) * vldf(scale3 + k) + vldf(off3 + k);
      part += v * P.W3[k * 4 + c];
    }
    #pragma unroll
    for (int m = 4; m < 64; m <<= 1) part += __shfl_xor(part, m, 64);
    if (Le < 4) P.out[row * 4 + Le] = part + P.b3[Le];
  }
}

extern "C" void kernel_launch(void* const* d_in, const int* in_sizes, int n_in,
                              void* d_out, int out_size, void* d_ws, size_t ws_size,
                              hipStream_t stream) {
  if (ws_size < (size_t)WS_NEED) return;
  (void)hipFuncSetAttribute((const void*)conv_lstm,
                            hipFuncAttributeMaxDynamicSharedMemorySize, LDS_BYTES);
  Params prm;
  prm.t1  = (const int*)d_in[0];
  prm.t2  = (const int*)d_in[1];
  prm.t3  = (const int*)d_in[2];
  prm.emb = (const float*)d_in[3];
  prm.lW  = (const float*)d_in[4];
  prm.lB  = (const float*)d_in[5];
  prm.g1  = (const float*)d_in[6];  prm.be1 = (const float*)d_in[7];
  prm.W1  = (const float*)d_in[8];  prm.b1  = (const float*)d_in[9];
  prm.g2  = (const float*)d_in[10]; prm.be2 = (const float*)d_in[11];
  prm.W2  = (const float*)d_in[12]; prm.b2  = (const float*)d_in[13];
  prm.g3  = (const float*)d_in[14]; prm.be3 = (const float*)d_in[15];
  prm.W3  = (const float*)d_in[16]; prm.b3  = (const float*)d_in[17];
  prm.out = (float*)d_out;
  prm.ws  = (unsigned char*)d_ws;
  void* args[] = { &prm };
  hipLaunchCooperativeKernel((void*)conv_lstm, dim3(NBLK), dim3(NTHR), args,
                             LDS_BYTES, stream);
}

// Round 6
// 5134.044 us; speedup vs baseline: 2.2950x; 1.4968x over previous
//
#include <hip/hip_runtime.h>
#include <hip/hip_cooperative_groups.h>

namespace cg = cooperative_groups;

typedef _Float16 f16;
typedef f16 f16x8 __attribute__((ext_vector_type(8)));
typedef float f32x4 __attribute__((ext_vector_type(4)));
typedef unsigned int u32x4 __attribute__((ext_vector_type(4)));

#define TSTEPS 128
#define NBLK 256
#define NTHR 768
#define LDS_BYTES 147456           // 3 shared h-tile buffers x 48 KB (proven size)

// ---------------- workspace layout (bytes) ----------------
#define WT_BYTES (3ull*128*32*64*16)            // swizzled f16 weights: 12,582,912
#define H_OFF    (WT_BYTES)
#define H_BYTES  (3ull*2*768*512*2)             // h double buffers (f16): 4,718,592
#define S1_OFF   (H_OFF + H_BYTES)
#define O1_OFF   (S1_OFF + 1536*4)
#define Y1_OFF   (O1_OFF + 1536*4)
#define S2_OFF   (Y1_OFF + 256ull*1024*4)
#define O2_OFF   (S2_OFF + 1024*4)
#define Y2_OFF   (O2_OFF + 1024*4)
#define S3_OFF   (Y2_OFF + 256ull*102*4)
#define O3_OFF   (S3_OFF + 128*4)
#define BAR_OFF  (O3_OFF + 128*4)               // flag counters (zeroed in init)
#define WS_NEED  (BAR_OFF + 2048)

struct Params {
  const int *t1, *t2, *t3;
  const float *emb, *lW, *lB;
  const float *g1, *be1, *W1, *b1;
  const float *g2, *be2, *W2, *b2;
  const float *g3, *be3, *W3, *b3;
  float* out;
  unsigned char* ws;
};

__device__ __forceinline__ float sigmf(float x) {
  x = fminf(fmaxf(x, -30.f), 30.f);
  return 1.f / (1.f + __expf(-x));
}
__device__ __forceinline__ float tanhf_(float x) {
  x = fminf(fmaxf(x, -15.f), 15.f);
  float e = __expf(-2.f * x);
  return (1.f - e) / (1.f + e);
}
__device__ __forceinline__ float wsum(float v) {
  #pragma unroll
  for (int m = 1; m < 64; m <<= 1) v += __shfl_xor(v, m, 64);
  return v;
}
__device__ __forceinline__ float vldh(const f16* p) {
  unsigned short u = *(volatile const unsigned short*)p;
  union { unsigned short s; f16 h; } cv; cv.s = u;
  return (float)cv.h;
}
__device__ __forceinline__ float vldf(const float* p) { return *(volatile const float*)p; }
__device__ __forceinline__ void  vstf(float* p, float v) { *(volatile float*)p = v; }
__device__ __forceinline__ f16x8 emb_frag(const float* e) {
  float4 fa = *(const float4*)e, fb = *(const float4*)(e + 4);
  f16x8 v;
  v[0]=(f16)fa.x; v[1]=(f16)fa.y; v[2]=(f16)fa.z; v[3]=(f16)fa.w;
  v[4]=(f16)fb.x; v[5]=(f16)fb.y; v[6]=(f16)fb.z; v[7]=(f16)fb.w;
  return v;
}

// Relaxed flag barrier (R5-proven): no acquire/release cache ops, L2 stays warm.
__device__ __forceinline__ void bar_arrive_wait(unsigned* ctr, unsigned target, int tid) {
  __syncthreads();
  if (tid == 0)
    __hip_atomic_fetch_add(ctr, 1u, __ATOMIC_RELAXED, __HIP_MEMORY_SCOPE_AGENT);
  if (tid < 64) {
    while (__hip_atomic_load(ctr, __ATOMIC_RELAXED, __HIP_MEMORY_SCOPE_AGENT) < target)
      __builtin_amdgcn_s_sleep(8);
  }
  __syncthreads();
}

#define MFMA16(a,b,c) __builtin_amdgcn_mfma_f32_16x16x32_f16((a),(b),(c),0,0,0)

// 256 blocks x 768 threads, 1 block/CU (proven cooperative shape).
__global__ __launch_bounds__(NTHR, 3) void conv_lstm(Params P) {
  cg::grid_group grid = cg::this_grid();
  const int bid = blockIdx.x, tid = threadIdx.x;

  extern __shared__ __align__(16) f16 smem[];   // H0|H1|H2, 24576 f16 (48 KB) each

  f16*      WT   = (f16*)(P.ws);
  f16*      Hb   = (f16*)(P.ws + H_OFF);
  unsigned* bar  = (unsigned*)(P.ws + BAR_OFF); // [rg*16] 16 rg-ctrs, [256] grid ctr
  unsigned* gctr = bar + 256;

  // ---- init: weight swizzle into MFMA B-fragment order + zero h + zero ctrs ----
  {
    const int gt = bid * NTHR + tid;
    for (int slot = gt; slot < 786432; slot += NBLK * NTHR) {
      int lane = slot & 63, kkg = (slot >> 6) & 31, g16 = (slot >> 11) & 127, l = slot >> 18;
      int k = kkg * 32 + (lane >> 4) * 8;
      int p = g16 * 16 + (lane & 15);             // permuted gate-col: p = 4u+g
      int n = (p & 3) * 512 + (p >> 2);           // original col: g*512+u
      const float* s = P.lW + ((size_t)l * 1024 + k) * 2048 + n;
      f16x8 v;
      #pragma unroll
      for (int j = 0; j < 8; j++) v[j] = (f16)s[(size_t)j * 2048];
      *(f16x8*)(WT + (size_t)slot * 8) = v;
    }
    uint4 z4; z4.x = z4.y = z4.z = z4.w = 0u;
    uint4* zp = (uint4*)(P.ws + H_OFF);
    for (int i = gt; i < 294912; i += NBLK * NTHR) zp[i] = z4;
    if (bid == 0 && tid < 512) bar[tid] = 0u;
  }
  grid.sync();   // the ONE fence-ful sync: publishes WT / h-zeros / ctr-zeros

  // ---- thread geometry: 16 rowgroups x 16 colgroups ----
  const int sb   = tid >> 8;                      // layer sub-group (256 thr = 4 waves)
  const int tid2 = tid & 255;
  const int w2   = tid2 >> 6;                     // wave-in-subgroup: 32-pcol slice
  const int wv   = tid >> 6;                      // global wave id [0,12)
  const int L    = tid & 63;
  const int r16  = L & 15, quad = L >> 4;
  const int s4   = L & 3, r16q = r16 >> 2;
  const int rg   = bid >> 4, cgi = bid & 15;
  const int row0 = rg * 48;
  unsigned* rgc  = bar + rg * 16;

  const int ug = cgi * 32 + w2 * 8 + r16q;        // unit base for this lane
  float bia[2][4];
  #pragma unroll
  for (int ct2 = 0; ct2 < 2; ++ct2)
    #pragma unroll
    for (int g = 0; g < 4; ++g)
      bia[ct2][g] = P.lB[sb * 2048 + g * 512 + ug + ct2 * 4];
  float c6[6] = {0.f, 0.f, 0.f, 0.f, 0.f, 0.f};   // persistent c-state (VGPR)

  const size_t lstride = 768 * 512;
  const f16x8* Bb = (const f16x8*)WT
      + ((size_t)(sb * 128 + cgi * 8 + w2 * 2) * 32) * 64 + L;
  f16* stash = smem + sb * 1920;                  // [48][40] f16, overlaps H0 post-MFMA

  // ---- wavefront: 3 layers in parallel; h-tiles staged ONCE into shared LDS ----
  for (int s = 0; s < TSTEPS + 2; ++s) {
    const int t = s - sb;
    const bool act = (t >= 0 && t < TSTEPS);
    f16* hdo = Hb + (size_t)(sb * 2 + (t & 1)) * lstride;

    // shared h-tile sources (slot arithmetic: (x)&1 is well-defined for x<0)
    const f16* hs0 = Hb + (size_t)(0 * 2 + ((s - 1) & 1)) * lstride;  // h_l0[s-1]
    const f16* hs1 = Hb + (size_t)(1 * 2 + ((s - 2) & 1)) * lstride;  // h_l1[s-2]
    const f16* hs2 = Hb + (size_t)(2 * 2 + ((s - 3) & 1)) * lstride;  // h_l2[s-3]

    // ---- stage: all 12 waves fill H0|H1|H2 (48 frag-blocks of 1 KB each) ----
    // (entering here, the previous step's rg-barrier guarantees LDS is free)
    #pragma unroll
    for (int i = 0; i < 12; ++i) {
      int fb = wv * 12 + i;                       // [0,144)
      int buf = fb / 48, inner = fb - buf * 48;
      int kk = inner / 3, rt = inner - kk * 3;
      const f16* src = (buf == 0) ? hs0 : ((buf == 1) ? hs1 : hs2);
      int m = row0 + rt * 16 + r16;
      u32x4 v = *(volatile const u32x4*)(src + (size_t)m * 512 + kk * 32 + quad * 8);
      *(u32x4*)(smem + buf * 24576 + inner * 512 + L * 8) = v;
    }
    __syncthreads();

    f32x4 acc[3][2];
    #pragma unroll
    for (int a = 0; a < 3; a++)
      #pragma unroll
      for (int b = 0; b < 2; b++) acc[a][b] = (f32x4){0.f, 0.f, 0.f, 0.f};

    if (act) {
      // token/emb base pointers for layer 0 (per-lane row)
      const float *e0, *e1, *e2;
      if (sb == 0) {
        int m0 = row0 + r16, m1 = m0 + 16, m2 = m0 + 32;
        int b0 = m0 & 255, tx0 = m0 >> 8;
        int b1 = m1 & 255, tx1 = m1 >> 8;
        int b2 = m2 & 255, tx2 = m2 >> 8;
        const int* tp0 = (tx0 == 0) ? P.t1 : ((tx0 == 1) ? P.t2 : P.t3);
        const int* tp1 = (tx1 == 0) ? P.t1 : ((tx1 == 1) ? P.t2 : P.t3);
        const int* tp2 = (tx2 == 0) ? P.t1 : ((tx2 == 1) ? P.t2 : P.t3);
        e0 = P.emb + (size_t)tp0[b0 * TSTEPS + t] * 512;
        e1 = P.emb + (size_t)tp1[b1 * TSTEPS + t] * 512;
        e2 = P.emb + (size_t)tp2[b2 * TSTEPS + t] * 512;
      }
      const f16* xbuf = smem + (sb - 1) * 24576;  // valid for sb>0
      const f16* hbuf = smem + sb * 24576;

      // x-side: k in [0,512)
      #pragma unroll 4
      for (int kk = 0; kk < 16; ++kk) {
        f16x8 a0, a1, a2;
        if (sb == 0) {
          int k = kk * 32 + quad * 8;
          a0 = emb_frag(e0 + k); a1 = emb_frag(e1 + k); a2 = emb_frag(e2 + k);
        } else {
          a0 = *(const f16x8*)(xbuf + (kk * 3 + 0) * 512 + L * 8);
          a1 = *(const f16x8*)(xbuf + (kk * 3 + 1) * 512 + L * 8);
          a2 = *(const f16x8*)(xbuf + (kk * 3 + 2) * 512 + L * 8);
        }
        f16x8 b0 = Bb[kk * 64], b1 = Bb[kk * 64 + 2048];
        acc[0][0] = MFMA16(a0, b0, acc[0][0]);
        acc[1][0] = MFMA16(a1, b0, acc[1][0]);
        acc[2][0] = MFMA16(a2, b0, acc[2][0]);
        acc[0][1] = MFMA16(a0, b1, acc[0][1]);
        acc[1][1] = MFMA16(a1, b1, acc[1][1]);
        acc[2][1] = MFMA16(a2, b1, acc[2][1]);
      }
      // h-side: k in [512,1024)
      #pragma unroll 4
      for (int kk = 16; kk < 32; ++kk) {
        int in3 = (kk - 16) * 3;
        f16x8 a0 = *(const f16x8*)(hbuf + (in3 + 0) * 512 + L * 8);
        f16x8 a1 = *(const f16x8*)(hbuf + (in3 + 1) * 512 + L * 8);
        f16x8 a2 = *(const f16x8*)(hbuf + (in3 + 2) * 512 + L * 8);
        f16x8 b0 = Bb[kk * 64], b1 = Bb[kk * 64 + 2048];
        acc[0][0] = MFMA16(a0, b0, acc[0][0]);
        acc[1][0] = MFMA16(a1, b0, acc[1][0]);
        acc[2][0] = MFMA16(a2, b0, acc[2][0]);
        acc[0][1] = MFMA16(a0, b1, acc[0][1]);
        acc[1][1] = MFMA16(a1, b1, acc[1][1]);
        acc[2][1] = MFMA16(a2, b1, acc[2][1]);
      }
    }
    __syncthreads();                              // all LDS reads done -> stash may overwrite

    // ---- elementwise: 4x4 lane<->reg transpose -> c/h; h out via LDS stash ----
    if (act) {
      #pragma unroll
      for (int rt = 0; rt < 3; ++rt) {
        #pragma unroll
        for (int ct2 = 0; ct2 < 2; ++ct2) {
          float x0 = acc[rt][ct2][0], x1 = acc[rt][ct2][1];
          float x2 = acc[rt][ct2][2], x3 = acc[rt][ct2][3];
          float a, b;
          a = (s4 & 1) ? x0 : x1;  b = (s4 & 1) ? x2 : x3;
          a = __shfl_xor(a, 1, 64); b = __shfl_xor(b, 1, 64);
          if (s4 & 1) { x0 = a; x2 = b; } else { x1 = a; x3 = b; }
          a = (s4 & 2) ? x0 : x2;  b = (s4 & 2) ? x1 : x3;
          a = __shfl_xor(a, 2, 64); b = __shfl_xor(b, 2, 64);
          if (s4 & 2) { x0 = a; x1 = b; } else { x2 = a; x3 = b; }
          float vi = x0 + bia[ct2][0], vj = x1 + bia[ct2][1];
          float vf = x2 + bia[ct2][2], vo = x3 + bia[ct2][3];
          int j = rt * 2 + ct2;
          float cn = sigmf(vf) * c6[j] + sigmf(vi) * tanhf_(vj);
          c6[j] = cn;
          int rl = rt * 16 + quad * 4 + s4;       // [0,48)
          int cl = w2 * 8 + ct2 * 4 + r16q;       // [0,32)
          stash[rl * 40 + cl] = (f16)(sigmf(vo) * tanhf_(cn));
        }
      }
    }
    __syncthreads();
    if (act && tid2 < 192) {                      // h-store: 16 B write-through to L3
      int rl = tid2 >> 2, sg = tid2 & 3;
      u32x4 v = *(const u32x4*)(stash + rl * 40 + sg * 8);
      *(volatile u32x4*)(hdo + (size_t)(row0 + rl) * 512 + cgi * 32 + sg * 8) = v;
    }
    bar_arrive_wait(rgc, 16u * (unsigned)(s + 1), tid);  // per-rg (16 blocks), relaxed
  }

  // ---------------- epilogue: relaxed grid barriers + volatile buffers ----------------
  float* scale1 = (float*)(P.ws + S1_OFF); float* off1 = (float*)(P.ws + O1_OFF);
  float* y1    = (float*)(P.ws + Y1_OFF);
  float* scale2 = (float*)(P.ws + S2_OFF); float* off2 = (float*)(P.ws + O2_OFF);
  float* y2    = (float*)(P.ws + Y2_OFF);
  float* scale3 = (float*)(P.ws + S3_OFF); float* off3 = (float*)(P.ws + O3_OFF);
  const f16* h2f = Hb + (size_t)(2 * 2 + 1) * lstride;   // top layer, t=127 (slot 1)

  bar_arrive_wait(gctr, 256u, tid);               // all rgs done -> h2f complete

  const int wvg = bid * 12 + wv;
  const int Le  = tid & 63;
  const float SC = 1.0507009873554805f, AL = 1.6732632423543772f;

  // E1: BN1 -> fused scale/offset for 1536 cols (one wave per col)
  if (wvg < 1536) {
    int c = wvg, tx = c >> 9, u = c & 511;
    float sm = 0.f, s2 = 0.f;
    for (int r = Le; r < 256; r += 64) {
      float v = vldh(h2f + (size_t)(tx * 256 + r) * 512 + u);
      sm += v; s2 += v * v;
    }
    sm = wsum(sm); s2 = wsum(s2);
    if (Le == 0) {
      float mu = sm * (1.f / 256.f);
      float var = s2 * (1.f / 256.f) - mu * mu;
      float sc = rsqrtf(var + 1e-3f) * P.g1[c];
      vstf(scale1 + c, sc); vstf(off1 + c, P.be1[c] - mu * sc);
    }
  }
  bar_arrive_wait(gctr, 512u, tid);

  // E2: y1 = selu(rep_n @ W1 + b1): block = 16-row slab x 64-col slice, slab in LDS
  {
    const int rb16 = (bid >> 4) * 16, cb = bid & 15;
    f16*   slab = smem;                           // [16][1536] f16 (49,152 B)
    float* scl  = (float*)(smem + 24576);         // [1536]
    float* ofl  = scl + 1536;                     // [1536]
    for (int e = tid; e < 3072; e += NTHR) {      // 16-B chunks of the slab
      int r = e / 192, seg = e % 192;
      int u8 = seg * 8, tx = u8 >> 9, u = u8 & 511;
      u32x4 v = *(volatile const u32x4*)(h2f + (size_t)(tx * 256 + rb16 + r) * 512 + u);
      *(u32x4*)(slab + r * 1536 + seg * 8) = v;
    }
    for (int k2 = tid; k2 < 1536; k2 += NTHR) { scl[k2] = vldf(scale1 + k2); ofl[k2] = vldf(off1 + k2); }
    __syncthreads();
    int rgrp = tid >> 6;
    if (rgrp < 8) {
      int c = cb * 64 + (tid & 63);
      int r0 = rgrp * 2, r1 = r0 + 1;
      float a0 = 0.f, a1 = 0.f;
      for (int k = 0; k < 1536; ++k) {
        float w = P.W1[(size_t)k * 1024 + c];
        float sck = scl[k], ofk = ofl[k];
        a0 += ((float)slab[r0 * 1536 + k] * sck + ofk) * w;
        a1 += ((float)slab[r1 * 1536 + k] * sck + ofk) * w;
      }
      float x0 = a0 + P.b1[c], x1 = a1 + P.b1[c];
      vstf(y1 + (size_t)(rb16 + r0) * 1024 + c, SC * (x0 > 0.f ? x0 : AL * expm1f(x0)));
      vstf(y1 + (size_t)(rb16 + r1) * 1024 + c, SC * (x1 > 0.f ? x1 : AL * expm1f(x1)));
    }
  }
  bar_arrive_wait(gctr, 768u, tid);

  // E3: BN2 scale/offset for 1024 cols (one wave per col)
  if (wvg < 1024) {
    int c = wvg;
    float sm = 0.f, s2 = 0.f;
    for (int r = Le; r < 256; r += 64) {
      float v = vldf(y1 + (size_t)r * 1024 + c);
      sm += v; s2 += v * v;
    }
    sm = wsum(sm); s2 = wsum(s2);
    if (Le == 0) {
      float mu = sm * (1.f / 256.f);
      float var = s2 * (1.f / 256.f) - mu * mu;
      float sc = rsqrtf(var + 1e-3f) * P.g2[c];
      vstf(scale2 + c, sc); vstf(off2 + c, P.be2[c] - mu * sc);
    }
  }
  bar_arrive_wait(gctr, 1024u, tid);

  // E4: y2 = selu(y1n @ W2 + b2): one wave per batch row
  if (wvg < 256) {
    int row = wvg;
    int c0 = Le, c1 = Le + 64;
    float a0 = 0.f, a1 = 0.f;
    for (int k = 0; k < 1024; ++k) {
      float v = vldf(y1 + (size_t)row * 1024 + k) * vldf(scale2 + k) + vldf(off2 + k);
      a0 += v * P.W2[(size_t)k * 102 + c0];
      if (c1 < 102) a1 += v * P.W2[(size_t)k * 102 + c1];
    }
    {
      float x = a0 + P.b2[c0];
      if (c0 < 102) vstf(y2 + (size_t)row * 102 + c0, SC * (x > 0.f ? x : AL * expm1f(x)));
    }
    if (c1 < 102) {
      float x = a1 + P.b2[c1];
      vstf(y2 + (size_t)row * 102 + c1, SC * (x > 0.f ? x : AL * expm1f(x)));
    }
  }
  bar_arrive_wait(gctr, 1280u, tid);

  // E5: BN3 scale/offset for 102 cols (one wave per col)
  if (wvg < 102) {
    int c = wvg;
    float sm = 0.f, s2 = 0.f;
    for (int r = Le; r < 256; r += 64) {
      float v = vldf(y2 + (size_t)r * 102 + c);
      sm += v; s2 += v * v;
    }
    sm = wsum(sm); s2 = wsum(s2);
    if (Le == 0) {
      float mu = sm * (1.f / 256.f);
      float var = s2 * (1.f / 256.f) - mu * mu;
      float sc = rsqrtf(var + 1e-3f) * P.g3[c];
      vstf(scale3 + c, sc); vstf(off3 + c, P.be3[c] - mu * sc);
    }
  }
  bar_arrive_wait(gctr, 1536u, tid);

  // E6: out = y2n @ W3 + b3: one wave per batch row
  if (wvg < 256) {
    int row = wvg;
    int c = Le & 3, kq = Le >> 2;
    float part = 0.f;
    for (int k = kq; k < 102; k += 16) {
      float v = vldf(y2 + (size_t)row * 102 + k) * vldf(scale3 + k) + vldf(off3 + k);
      part += v * P.W3[k * 4 + c];
    }
    #pragma unroll
    for (int m = 4; m < 64; m <<= 1) part += __shfl_xor(part, m, 64);
    if (Le < 4) P.out[row * 4 + Le] = part + P.b3[Le];
  }
}

extern "C" void kernel_launch(void* const* d_in, const int* in_sizes, int n_in,
                              void* d_out, int out_size, void* d_ws, size_t ws_size,
                              hipStream_t stream) {
  if (ws_size < (size_t)WS_NEED) return;
  (void)hipFuncSetAttribute((const void*)conv_lstm,
                            hipFuncAttributeMaxDynamicSharedMemorySize, LDS_BYTES);
  Params prm;
  prm.t1  = (const int*)d_in[0];
  prm.t2  = (const int*)d_in[1];
  prm.t3  = (const int*)d_in[2];
  prm.emb = (const float*)d_in[3];
  prm.lW  = (const float*)d_in[4];
  prm.lB  = (const float*)d_in[5];
  prm.g1  = (const float*)d_in[6];  prm.be1 = (const float*)d_in[7];
  prm.W1  = (const float*)d_in[8];  prm.b1  = (const float*)d_in[9];
  prm.g2  = (const float*)d_in[10]; prm.be2 = (const float*)d_in[11];
  prm.W2  = (const float*)d_in[12]; prm.b2  = (const float*)d_in[13];
  prm.g3  = (const float*)d_in[14]; prm.be3 = (const float*)d_in[15];
  prm.W3  = (const float*)d_in[16]; prm.b3  = (const float*)d_in[17];
  prm.out = (float*)d_out;
  prm.ws  = (unsigned char*)d_ws;
  void* args[] = { &prm };
  hipLaunchCooperativeKernel((void*)conv_lstm, dim3(NBLK), dim3(NTHR), args,
                             LDS_BYTES, stream);
}